// Round 5
// baseline (540.918 us; speedup 1.0000x reference)
//
#include <hip/hip_runtime.h>
#include <cstddef>

// Bit-exact OpenBLAS-skylakex (KC=320) fp32 SNN.
// Chain order (PASSED r3/r4): k ascending, panel folds at k=320/640,
// ((P1+P2)+P3)+b1; LIF literal order; layer2 cur2=mm+b2 then m2*0.25+cur2,
// j ascending.
// r5: BROWS=32 -> grid 1024 (4 blocks/CU); global->reg prefetch of next tile;
// layer-2 on one wave (5 o's/lane, ballot-built interleaved masks, W2 scaled
// by 2^-(j>>2) so bit->operand is and+cvt, products exact).

constexpr int BROWS  = 32;
constexpr int BK     = 16;    // 784 = 49*16; KC=320 folds after tiles 19,39
constexpr int NJ     = 128;
constexpr int KDIM   = 784;
constexpr int NO     = 10;
constexpr int TSTEPS = 20;

__global__ __launch_bounds__(256, 4) void snn_fused(
    const float* __restrict__ x,
    const float* __restrict__ W1,
    const float* __restrict__ b1,
    const float* __restrict__ W2,
    const float* __restrict__ b2,
    float* __restrict__ out,
    int B)
{
    __shared__ alignas(16) float xs[BK][36];      // [kk][row(32)+pad]
    __shared__ alignas(16) float ws[BK][140];     // [kk][granule-padded 128 cols]
    __shared__ alignas(16) float w2a[NJ][2][8];   // [j][half][o 0..4 + pad], *2^-(j>>2)
    __shared__ alignas(16) unsigned smask[2][BROWS][4];  // parity interleaved masks

    const int t  = threadIdx.x;
    const int tx = t & 31;                         // col group: j = tx*4+cc
    const int ty = t >> 5;                         // row group: r = ty*4+rr
    const int r0 = blockIdx.x * BROWS;

    // ---- one-time staging: W2 (half-split, 2^-(j>>2) scaled) ----
    for (int e = t; e < NJ * 16; e += 256) {
        int c = e & 7, h = (e >> 3) & 1, j = e >> 4;
        float v = 0.0f;
        if (c < 5) {
            float sc = __int_as_float((127 - (j >> 2)) << 23);  // 2^-(j>>2), exact
            v = W2[(h * 5 + c) * NJ + j] * sc;
        }
        w2a[j][h][c] = v;
    }

    // ---- phase 1: fp32 GEMM, panel folds at k=320,640 ----
    float acc[4][4], cur[4][4];
    #pragma unroll
    for (int rr = 0; rr < 4; ++rr)
        #pragma unroll
        for (int cc = 0; cc < 4; ++cc) { acc[rr][cc] = 0.0f; cur[rr][cc] = 0.0f; }

    const int xrow = t >> 2, xkf = (t & 3) * 4;    // x stage (t<128): row, 4-k
    const int wj   = t >> 1, wkf = (t & 1) * 8;    // W1 stage: col j, 8-k
    const int wph  = wj + 4 * (wj >> 5);           // granule-padded col
    const float* xrp = x  + (size_t)(r0 + xrow) * KDIM + xkf;
    const float* wrp = W1 + (size_t)wj * KDIM + wkf;

    float4 xv, wa, wb;
    if (t < 128) xv = *(const float4*)(xrp);
    wa = *(const float4*)(wrp);
    wb = *(const float4*)(wrp + 4);

    #pragma unroll 1
    for (int tt = 0; tt < 49; ++tt) {
        if (t < 128) {
            xs[xkf + 0][xrow] = xv.x; xs[xkf + 1][xrow] = xv.y;
            xs[xkf + 2][xrow] = xv.z; xs[xkf + 3][xrow] = xv.w;
        }
        float* wp = &ws[wkf][wph];                 // rows wkf..wkf+7, stride 140
        wp[0]   = wa.x; wp[140] = wa.y; wp[280] = wa.z; wp[420] = wa.w;
        wp[560] = wb.x; wp[700] = wb.y; wp[840] = wb.z; wp[980] = wb.w;
        __syncthreads();
        if (tt < 48) {                             // prefetch next tile -> regs
            const int k0n = (tt + 1) * BK;
            if (t < 128) xv = *(const float4*)(xrp + k0n);
            wa = *(const float4*)(wrp + k0n);
            wb = *(const float4*)(wrp + k0n + 4);
        }
        #pragma unroll
        for (int kk = 0; kk < BK; ++kk) {          // strict ascending k
            float4 xr = *(const float4*)&xs[kk][ty * 4];
            float4 wv = *(const float4*)&ws[kk][4 * tx + 4 * (tx >> 3)];
            float xf[4] = {xr.x, xr.y, xr.z, xr.w};
            float wf[4] = {wv.x, wv.y, wv.z, wv.w};
            #pragma unroll
            for (int rr = 0; rr < 4; ++rr)
                #pragma unroll
                for (int cc = 0; cc < 4; ++cc)
                    acc[rr][cc] = fmaf(xf[rr], wf[cc], acc[rr][cc]);
        }
        __syncthreads();
        if (tt == 19) {                            // end panel 1 [0,320)
            #pragma unroll
            for (int rr = 0; rr < 4; ++rr)
                #pragma unroll
                for (int cc = 0; cc < 4; ++cc) { cur[rr][cc] = acc[rr][cc]; acc[rr][cc] = 0.0f; }
        } else if (tt == 39) {                     // end panel 2 [320,640)
            #pragma unroll
            for (int rr = 0; rr < 4; ++rr)
                #pragma unroll
                for (int cc = 0; cc < 4; ++cc) { cur[rr][cc] = cur[rr][cc] + acc[rr][cc]; acc[rr][cc] = 0.0f; }
        }
    }
    {
        float4 bv = *(const float4*)(b1 + tx * 4);
        float bf[4] = {bv.x, bv.y, bv.z, bv.w};
        #pragma unroll
        for (int rr = 0; rr < 4; ++rr)
            #pragma unroll
            for (int cc = 0; cc < 4; ++cc)
                cur[rr][cc] = (cur[rr][cc] + acc[rr][cc]) + bf[cc];   // +P3, +b1
    }

    // ---- phase 2: LIF dynamics ----
    float mem1[4][4];
    #pragma unroll
    for (int rr = 0; rr < 4; ++rr)
        #pragma unroll
        for (int cc = 0; cc < 4; ++cc) mem1[rr][cc] = 0.0f;

    const int w  = t >> 6;                         // wave id
    const int g  = (t >> 5) & 1;                   // half-wave
    const int crow = t & 31;                       // consumer: row
    const int ch   = (t >> 5) & 1;                 // consumer: o-half (t<64)
    float m2[5]  = {0.f, 0.f, 0.f, 0.f, 0.f};
    float cnt[5] = {0.f, 0.f, 0.f, 0.f, 0.f};
    float b2r[5];
    if (t < 64) {
        #pragma unroll
        for (int c = 0; c < 5; ++c) b2r[c] = b2[ch * 5 + c];
    }
    float* rec = out + (size_t)B * NO;

    #pragma unroll 1
    for (int st = 0; st < TSTEPS; ++st) {
        const int p = st & 1;
        bool  sp[4][4];
        #pragma unroll
        for (int rr = 0; rr < 4; ++rr) {
            float s0[4];
            #pragma unroll
            for (int cc = 0; cc < 4; ++cc) {
                float m = fmaf(mem1[rr][cc], 0.25f, cur[rr][cc]);  // *0.25 exact
                bool  s = (m - 1.0f) > 0.0f;
                sp[rr][cc] = s;
                s0[cc] = s ? 1.0f : 0.0f;
                mem1[rr][cc] = s ? 0.0f : m;
            }
            float4 f; f.x = s0[0]; f.y = s0[1]; f.z = s0[2]; f.w = s0[3];
            *(float4*)&rec[((size_t)st * B + (size_t)(r0 + ty * 4 + rr)) * NJ + tx * 4] = f;
        }
        #pragma unroll
        for (int rr = 0; rr < 4; ++rr)
            #pragma unroll
            for (int jj = 0; jj < 4; ++jj) {       // interleaved: bit q <-> j=4q+jj
                unsigned long long bm = __ballot(sp[rr][jj]);
                if ((t & 31) == jj)
                    smask[p][w * 8 + g * 4 + rr][jj] = (unsigned)(bm >> (g * 32));
            }
        __syncthreads();
        if (t < 64) {                              // consumer wave: layer 2
            uint4 mr = *(const uint4*)&smask[p][crow][0];
            unsigned mw[4] = {mr.x, mr.y, mr.z, mr.w};
            float mm[5] = {0.f, 0.f, 0.f, 0.f, 0.f};
            for (int q = 0; q < 32; ++q) {
                #pragma unroll
                for (int s = 0; s < 4; ++s) {      // j = 4q+s, strict ascending
                    int j = 4 * q + s;
                    float f = (float)(mw[s] & (1u << q));        // 0 or 2^q, exact
                    const float* wp2 = &w2a[j][ch][0];
                    float4 w4 = *(const float4*)wp2;
                    float  w5 = wp2[4];
                    mm[0] = fmaf(f, w4.x, mm[0]);
                    mm[1] = fmaf(f, w4.y, mm[1]);
                    mm[2] = fmaf(f, w4.z, mm[2]);
                    mm[3] = fmaf(f, w4.w, mm[3]);
                    mm[4] = fmaf(f, w5,   mm[4]);
                }
            }
            #pragma unroll
            for (int c = 0; c < 5; ++c) {
                float cur2 = mm[c] + b2r[c];       // np: chain + b2
                float nm   = fmaf(m2[c], 0.25f, cur2);
                bool  s2   = (nm - 1.0f) > 0.0f;
                cnt[c] += s2 ? 1.0f : 0.0f;
                m2[c]  = s2 ? 0.0f : nm;
            }
        }
    }

    if (t < 64) {
        #pragma unroll
        for (int c = 0; c < 5; ++c)
            out[(size_t)(r0 + crow) * NO + ch * 5 + c] = cnt[c];
    }
}

extern "C" void kernel_launch(void* const* d_in, const int* in_sizes, int n_in,
                              void* d_out, int out_size, void* d_ws, size_t ws_size,
                              hipStream_t stream)
{
    const float* x  = (const float*)d_in[0];
    const float* W1 = (const float*)d_in[1];
    const float* b1 = (const float*)d_in[2];
    const float* W2 = (const float*)d_in[3];
    const float* b2 = (const float*)d_in[4];
    float* out = (float*)d_out;
    const int B = in_sizes[0] / KDIM;       // 32768
    snn_fused<<<B / BROWS, 256, 0, stream>>>(x, W1, b1, W2, b2, out, B);
}

// Round 7
// 498.636 us; speedup vs baseline: 1.0848x; 1.0848x over previous
//
#include <hip/hip_runtime.h>
#include <cstddef>

// Bit-exact OpenBLAS-skylakex (KC=320) fp32 SNN.
// Chain order (PASSED r3/r4/r5): k ascending, panel folds at k=320/640,
// ((P1+P2)+P3)+b1; LIF literal order; layer2 cur2=mm+b2 then m2*0.25+cur2,
// j ascending.
// r6 = r4 structure (BROWS=64, 4x8 tile, benign LDS layouts) +
//  - double-buffered xs/ws: ONE barrier per tile (was 2), and
//  - register prefetch of tile tt+1 issued before compute of tt
//    (global latency hidden under 16-kk FMA block),
//  - nontemporal rec stores (328 MB streamed, keep L2 for x/W1)
//    via native ext_vector_type (HIP float4 class is rejected by the builtin).

typedef float f32x4 __attribute__((ext_vector_type(4)));

constexpr int BROWS  = 64;
constexpr int BK     = 16;    // 784 = 49*16; KC=320 folds after tiles 19,39
constexpr int NJ     = 128;
constexpr int KDIM   = 784;
constexpr int NO     = 10;
constexpr int TSTEPS = 20;

__global__ __launch_bounds__(256, 2) void snn_fused(
    const float* __restrict__ x,
    const float* __restrict__ W1,
    const float* __restrict__ b1,
    const float* __restrict__ W2,
    const float* __restrict__ b2,
    float* __restrict__ out,
    int B)
{
    __shared__ alignas(16) float xs[2][BK][68];    // [buf][kk][row(64)+pad]
    __shared__ alignas(16) float ws[2][BK][192];   // [buf][kk][16 chunks * 12]
    __shared__ alignas(16) float4 w2s[NJ][3];      // [j][og]: W2[og*4+c][j]*2^-(j&31)
    __shared__ unsigned smaskW[2][BROWS][17];      // parity row masks
    __shared__ float b2s[12];

    const int t  = threadIdx.x;
    const int tx = t & 15;                         // col group: j = tx*8+jj
    const int ty = t >> 4;                         // row group: r = ty*4+rr
    const int r0 = blockIdx.x * BROWS;

    // ---- one-time staging: W2 (o-transposed, scaled), b2 ----
    for (int e = t; e < NJ * 3; e += 256) {
        int og = e % 3, j = e / 3;
        float sc = __int_as_float((127 - (j & 31)) << 23);   // 2^-(j&31), exact
        float vv[4];
        #pragma unroll
        for (int c = 0; c < 4; ++c) {
            int o = og * 4 + c;
            vv[c] = (o < NO) ? W2[o * NJ + j] * sc : 0.0f;
        }
        float4 v; v.x = vv[0]; v.y = vv[1]; v.z = vv[2]; v.w = vv[3];
        w2s[j][og] = v;
    }
    if (t < 12) b2s[t] = (t < NO) ? b2[t] : 0.0f;

    // ---- phase 1: fp32 GEMM, panel folds at k=320,640 ----
    float acc[4][8], cur[4][8];
    #pragma unroll
    for (int rr = 0; rr < 4; ++rr)
        #pragma unroll
        for (int jj = 0; jj < 8; ++jj) { acc[rr][jj] = 0.0f; cur[rr][jj] = 0.0f; }

    const int xrow = t >> 2, xkf = (t & 3) * 4;    // x stage: row, 4-k chunk
    const int wj   = t >> 1, wkf = (t & 1) * 8;    // W1 stage: j, 8-k chunk
    const int wco  = wj >> 3, wci = wj & 7;        // chunk / intra
    const float* xrp = x  + (size_t)(r0 + xrow) * KDIM + xkf;
    const float* wrp = W1 + (size_t)wj * KDIM + wkf;

    // preload tile 0 -> regs -> buf 0
    float4 xv = *(const float4*)(xrp);
    float4 wa = *(const float4*)(wrp);
    float4 wb = *(const float4*)(wrp + 4);
    {
        xs[0][xkf + 0][xrow] = xv.x; xs[0][xkf + 1][xrow] = xv.y;
        xs[0][xkf + 2][xrow] = xv.z; xs[0][xkf + 3][xrow] = xv.w;
        float* wp0 = &ws[0][wkf][wco * 12 + wci];  // rows wkf..wkf+7, stride 192
        wp0[0]    = wa.x; wp0[192]  = wa.y; wp0[384]  = wa.z; wp0[576]  = wa.w;
        wp0[768]  = wb.x; wp0[960]  = wb.y; wp0[1152] = wb.z; wp0[1344] = wb.w;
    }
    __syncthreads();

    #pragma unroll 1
    for (int tt = 0; tt < 49; ++tt) {
        const int cb = tt & 1;
        if (tt < 48) {                             // prefetch next tile -> regs
            const int k0n = (tt + 1) * BK;
            xv = *(const float4*)(xrp + k0n);
            wa = *(const float4*)(wrp + k0n);
            wb = *(const float4*)(wrp + k0n + 4);
        }
        #pragma unroll
        for (int kk = 0; kk < BK; ++kk) {          // strict ascending k
            float4 xr  = *(const float4*)&xs[cb][kk][ty * 4];
            float4 wva = *(const float4*)&ws[cb][kk][tx * 12];
            float4 wvb = *(const float4*)&ws[cb][kk][tx * 12 + 4];
            float xf[4] = {xr.x, xr.y, xr.z, xr.w};
            float wf[8] = {wva.x, wva.y, wva.z, wva.w, wvb.x, wvb.y, wvb.z, wvb.w};
            #pragma unroll
            for (int rr = 0; rr < 4; ++rr)
                #pragma unroll
                for (int jj = 0; jj < 8; ++jj)
                    acc[rr][jj] = fmaf(xf[rr], wf[jj], acc[rr][jj]);
        }
        if (tt == 19) {                            // end panel 1 [0,320)
            #pragma unroll
            for (int rr = 0; rr < 4; ++rr)
                #pragma unroll
                for (int jj = 0; jj < 8; ++jj) { cur[rr][jj] = acc[rr][jj]; acc[rr][jj] = 0.0f; }
        } else if (tt == 39) {                     // end panel 2 [320,640)
            #pragma unroll
            for (int rr = 0; rr < 4; ++rr)
                #pragma unroll
                for (int jj = 0; jj < 8; ++jj) { cur[rr][jj] = cur[rr][jj] + acc[rr][jj]; acc[rr][jj] = 0.0f; }
        }
        if (tt < 48) {                             // store prefetched tile
            const int nb = cb ^ 1;
            xs[nb][xkf + 0][xrow] = xv.x; xs[nb][xkf + 1][xrow] = xv.y;
            xs[nb][xkf + 2][xrow] = xv.z; xs[nb][xkf + 3][xrow] = xv.w;
            float* wp0 = &ws[nb][wkf][wco * 12 + wci];
            wp0[0]    = wa.x; wp0[192]  = wa.y; wp0[384]  = wa.z; wp0[576]  = wa.w;
            wp0[768]  = wb.x; wp0[960]  = wb.y; wp0[1152] = wb.z; wp0[1344] = wb.w;
        }
        __syncthreads();                           // ONE barrier per tile
    }
    {
        const float* b1p = b1 + tx * 8;
        float4 ba = *(const float4*)b1p, bb = *(const float4*)(b1p + 4);
        float bf[8] = {ba.x, ba.y, ba.z, ba.w, bb.x, bb.y, bb.z, bb.w};
        #pragma unroll
        for (int rr = 0; rr < 4; ++rr)
            #pragma unroll
            for (int jj = 0; jj < 8; ++jj)
                cur[rr][jj] = (cur[rr][jj] + acc[rr][jj]) + bf[jj];   // +P3, +b1
    }

    // ---- phase 2: LIF dynamics (r4 verbatim, nontemporal rec stores) ----
    float mem1[4][8];
    #pragma unroll
    for (int rr = 0; rr < 4; ++rr)
        #pragma unroll
        for (int jj = 0; jj < 8; ++jj) mem1[rr][jj] = 0.0f;

    const int row_l2 = t & 63;                     // layer-2: row
    const int og     = t >> 6;                     // o-group (wave-uniform); 3=idle
    float m2[4]  = {0.f, 0.f, 0.f, 0.f};
    float cnt[4] = {0.f, 0.f, 0.f, 0.f};
    float* rec = out + (size_t)B * NO;

    #pragma unroll 1
    for (int st = 0; st < TSTEPS; ++st) {
        const int p = st & 1;
        #pragma unroll
        for (int rr = 0; rr < 4; ++rr) {
            unsigned bt = 0;
            float s0[8];
            #pragma unroll
            for (int jj = 0; jj < 8; ++jj) {
                float m = fmaf(mem1[rr][jj], 0.25f, cur[rr][jj]);  // *0.25 exact
                float v = m - 1.0f;
                bool  s = v > 0.0f;
                s0[jj] = s ? 1.0f : 0.0f;
                mem1[rr][jj] = s ? 0.0f : m;
                bt |= s ? (1u << jj) : 0u;
            }
            size_t base = ((size_t)st * B + (size_t)(r0 + ty * 4 + rr)) * NJ + tx * 8;
            f32x4 fa = {s0[0], s0[1], s0[2], s0[3]};
            f32x4 fb = {s0[4], s0[5], s0[6], s0[7]};
            __builtin_nontemporal_store(fa, (f32x4*)&rec[base]);
            __builtin_nontemporal_store(fb, (f32x4*)&rec[base + 4]);
            ((unsigned char*)&smaskW[p][ty * 4 + rr][0])[tx] = (unsigned char)bt;
        }
        __syncthreads();
        if (og < 3) {
            unsigned mw[4];
            #pragma unroll
            for (int w = 0; w < 4; ++w) mw[w] = smaskW[p][row_l2][w];
            float mm[4] = {0.f, 0.f, 0.f, 0.f};
            #pragma unroll
            for (int w = 0; w < 4; ++w) {
                unsigned bits = mw[w];
                #pragma unroll
                for (int b = 0; b < 32; ++b) {     // strict ascending j
                    float f = (float)(bits & (1u << b));      // 0 or 2^b, exact
                    float4 wv = w2s[w * 32 + b][og];          // W2 * 2^-b
                    mm[0] = fmaf(f, wv.x, mm[0]);
                    mm[1] = fmaf(f, wv.y, mm[1]);
                    mm[2] = fmaf(f, wv.z, mm[2]);
                    mm[3] = fmaf(f, wv.w, mm[3]);
                }
            }
            #pragma unroll
            for (int c = 0; c < 4; ++c) {
                float cur2 = mm[c] + b2s[og * 4 + c];   // np: chain + b2
                float nm   = fmaf(m2[c], 0.25f, cur2);  // then decay add (exact mul)
                float v2   = nm - 1.0f;
                bool  s2   = v2 > 0.0f;
                cnt[c] += s2 ? 1.0f : 0.0f;
                m2[c]  = s2 ? 0.0f : nm;
            }
        }
    }

    if (og < 3) {
        #pragma unroll
        for (int c = 0; c < 4; ++c) {
            int o = og * 4 + c;
            if (o < NO) out[(size_t)(r0 + row_l2) * NO + o] = cnt[c];
        }
    }
}

extern "C" void kernel_launch(void* const* d_in, const int* in_sizes, int n_in,
                              void* d_out, int out_size, void* d_ws, size_t ws_size,
                              hipStream_t stream)
{
    const float* x  = (const float*)d_in[0];
    const float* W1 = (const float*)d_in[1];
    const float* b1 = (const float*)d_in[2];
    const float* W2 = (const float*)d_in[3];
    const float* b2 = (const float*)d_in[4];
    float* out = (float*)d_out;
    const int B = in_sizes[0] / KDIM;       // 32768
    snn_fused<<<B / BROWS, 256, 0, stream>>>(x, W1, b1, W2, b2, out, B);
}